// Round 1
// baseline (533.831 us; speedup 1.0000x reference)
//
#include <hip/hip_runtime.h>
#include <stdint.h>

typedef __attribute__((ext_vector_type(8))) short bf8_t;   // 8 x bf16 (raw bits)
typedef __attribute__((ext_vector_type(4))) float f4_t;

#define DEV __device__ __forceinline__

constexpr int S_ = 1024;
constexpr int R_ = 1025;          // 2K+1
constexpr float SCALE_ = 0.07216878364870322f;  // 1/sqrt(3*64)

DEV float bf2f(unsigned short u) { union { unsigned int i; float f; } v; v.i = ((unsigned int)u) << 16; return v.f; }
DEV unsigned short f2bf(float f) {
  union { float fv; unsigned int i; } v; v.fv = f;
  unsigned int r = v.i + 0x7FFFu + ((v.i >> 16) & 1u);
  return (unsigned short)(r >> 16);
}

// ---------------- fp32 -> bf16 bulk conversion (8 tensors, one launch) ----
struct CvtArgs { const float* src[8]; unsigned short* dst[8]; int nchunks[8]; };

__global__ __launch_bounds__(256) void cvt_kernel(CvtArgs a, int total) {
  int idx = blockIdx.x * 256 + threadIdx.x;
  int step = gridDim.x * 256;
  for (; idx < total; idx += step) {
    int c = idx, s = 0;
    while (c >= a.nchunks[s]) { c -= a.nchunks[s]; ++s; }
    float4 v = ((const float4*)a.src[s])[c];
    ushort4 o;
    o.x = f2bf(v.x); o.y = f2bf(v.y); o.z = f2bf(v.z); o.w = f2bf(v.w);
    ((ushort4*)a.dst[s])[c] = o;
  }
}

// ---------------- generic bf16 GEMM: C = A * B^T (+bias), epilogue modes --
enum { MQKV = 0, MVT = 1, MREL = 2, MCTX = 3, MOUT = 4 };

template <int BM, int BN, int MODE>
__global__ __launch_bounds__(256) void gemm_bt(
    const unsigned short* __restrict__ A, int lda, long abst,
    const unsigned short* __restrict__ B, int ldb, long bbst,
    void* __restrict__ C, const float* __restrict__ bias,
    int M, int N, int Kd)
{
  constexpr int WM = BM / 2, WN = BN / 2, FM = WM / 16, FN = WN / 16;
  __shared__ unsigned short At[BM][40];   // BK=32 + 8 pad (2-way-free banks)
  __shared__ unsigned short Bt[BN][40];
  const int tid = threadIdx.x, lane = tid & 63, w = tid >> 6;
  const int wr = w >> 1, wc = w & 1;
  const int m0 = blockIdx.y * BM, n0 = blockIdx.x * BN;
  const int z = blockIdx.z;
  const unsigned short* Ab = A + (long)z * abst;
  const unsigned short* Bb = B + (long)z * bbst;

  f4_t acc[FM][FN];
#pragma unroll
  for (int i = 0; i < FM; ++i)
#pragma unroll
    for (int j = 0; j < FN; ++j) acc[i][j] = f4_t{0.f, 0.f, 0.f, 0.f};

  for (int k0 = 0; k0 < Kd; k0 += 32) {
    for (int c = tid; c < BM * 4; c += 256) {
      int row = c >> 2, c8 = (c & 3) * 8;
      int gm = m0 + row; if (gm > M - 1) gm = M - 1;
      *(int4*)&At[row][c8] = *(const int4*)(Ab + (long)gm * lda + k0 + c8);
    }
    for (int c = tid; c < BN * 4; c += 256) {
      int row = c >> 2, c8 = (c & 3) * 8;
      int gn = n0 + row; if (gn > N - 1) gn = N - 1;
      *(int4*)&Bt[row][c8] = *(const int4*)(Bb + (long)gn * ldb + k0 + c8);
    }
    __syncthreads();
    const int kk = (lane >> 4) * 8;
    bf8_t a[FM], b[FN];
#pragma unroll
    for (int fm = 0; fm < FM; ++fm) a[fm] = *(const bf8_t*)&At[wr * WM + fm * 16 + (lane & 15)][kk];
#pragma unroll
    for (int fn = 0; fn < FN; ++fn) b[fn] = *(const bf8_t*)&Bt[wc * WN + fn * 16 + (lane & 15)][kk];
#pragma unroll
    for (int fm = 0; fm < FM; ++fm)
#pragma unroll
      for (int fn = 0; fn < FN; ++fn)
        acc[fm][fn] = __builtin_amdgcn_mfma_f32_16x16x32_bf16(a[fm], b[fn], acc[fm][fn], 0, 0, 0);
    __syncthreads();
  }

#pragma unroll
  for (int fm = 0; fm < FM; ++fm)
#pragma unroll
    for (int fn = 0; fn < FN; ++fn)
#pragma unroll
      for (int r = 0; r < 4; ++r) {
        int row = wr * WM + fm * 16 + (lane >> 4) * 4 + r;
        int col = wc * WN + fn * 16 + (lane & 15);
        int m = m0 + row, n = n0 + col;
        if (m >= M || n >= N) continue;
        float v = acc[fm][fn][r];
        if (bias) v += bias[n];
        long off;
        if constexpr (MODE == MQKV)      off = (long)((m >> 10) * 12 + (n >> 6)) * 65536 + (m & 1023) * 64 + (n & 63);
        else if constexpr (MODE == MVT)  off = (long)((m >> 10) * 12 + (n >> 6)) * 65536 + (n & 63) * 1024 + (m & 1023);
        else if constexpr (MODE == MREL) off = (long)(n >> 6) * (R_ * 64) + (long)m * 64 + (n & 63);
        else if constexpr (MODE == MCTX) { int bb = z / 12, hh = z - bb * 12; off = (long)bb * 786432 + (long)m * 768 + hh * 64 + n; }
        else                             off = (long)m * 768 + n;
        if constexpr (MODE == MOUT) ((float*)C)[off] = v;
        else                        ((unsigned short*)C)[off] = f2bf(v);
      }
}

// ---------------- scores: cc + Toeplitz cp/pc, 64x64 tiles ----------------
__global__ __launch_bounds__(256) void scores_kernel(
    const unsigned short* __restrict__ Q, const unsigned short* __restrict__ Kc,
    const unsigned short* __restrict__ kr, const unsigned short* __restrict__ qr,
    unsigned short* __restrict__ Sc)
{
  const int bh = blockIdx.z, h = bh % 12;
  const int i0 = blockIdx.y * 64, j0 = blockIdx.x * 64;
  const int tid = threadIdx.x, lane = tid & 63, w = tid >> 6;
  const unsigned short* Qb = Q + (long)bh * (S_ * 64);
  const unsigned short* Kb = Kc + (long)bh * (S_ * 64);
  const unsigned short* krh = kr + (long)h * (R_ * 64);
  const unsigned short* qrh = qr + (long)h * (R_ * 64);
  const int rbase  = min(max(j0 - i0 - 63, -512), 512) + 512;
  const int rbase2 = min(max(i0 - j0 - 63, -512), 512) + 512;

  __shared__ unsigned short Tcp[64][136];
  __shared__ unsigned short Tpc[64][136];

  const int mh = w & 1, nq = w >> 1;   // wave tile for T GEMMs: 32 rows x 64 cols

  { // Phase 1: Tcp = Qtile(64x64) @ krWin(128x64)^T
    f4_t acc[2][4];
#pragma unroll
    for (int i = 0; i < 2; ++i)
#pragma unroll
      for (int j = 0; j < 4; ++j) acc[i][j] = f4_t{0.f, 0.f, 0.f, 0.f};
#pragma unroll
    for (int ks = 0; ks < 2; ++ks) {
      const int kk = ks * 32 + (lane >> 4) * 8;
      bf8_t a[2], b[4];
#pragma unroll
      for (int fm = 0; fm < 2; ++fm)
        a[fm] = *(const bf8_t*)(Qb + (long)(i0 + mh * 32 + fm * 16 + (lane & 15)) * 64 + kk);
#pragma unroll
      for (int fn = 0; fn < 4; ++fn) {
        int krow = rbase + nq * 64 + fn * 16 + (lane & 15);
        if (krow > 1024) krow = 1024;
        b[fn] = *(const bf8_t*)(krh + (long)krow * 64 + kk);
      }
#pragma unroll
      for (int fm = 0; fm < 2; ++fm)
#pragma unroll
        for (int fn = 0; fn < 4; ++fn)
          acc[fm][fn] = __builtin_amdgcn_mfma_f32_16x16x32_bf16(a[fm], b[fn], acc[fm][fn], 0, 0, 0);
    }
#pragma unroll
    for (int fm = 0; fm < 2; ++fm)
#pragma unroll
      for (int fn = 0; fn < 4; ++fn)
#pragma unroll
        for (int r = 0; r < 4; ++r)
          Tcp[mh * 32 + fm * 16 + (lane >> 4) * 4 + r][nq * 64 + fn * 16 + (lane & 15)] = f2bf(acc[fm][fn][r]);
  }

  { // Phase 2: Tpc = Ktile(64x64) @ qrWin(128x64)^T
    f4_t acc[2][4];
#pragma unroll
    for (int i = 0; i < 2; ++i)
#pragma unroll
      for (int j = 0; j < 4; ++j) acc[i][j] = f4_t{0.f, 0.f, 0.f, 0.f};
#pragma unroll
    for (int ks = 0; ks < 2; ++ks) {
      const int kk = ks * 32 + (lane >> 4) * 8;
      bf8_t a[2], b[4];
#pragma unroll
      for (int fm = 0; fm < 2; ++fm)
        a[fm] = *(const bf8_t*)(Kb + (long)(j0 + mh * 32 + fm * 16 + (lane & 15)) * 64 + kk);
#pragma unroll
      for (int fn = 0; fn < 4; ++fn) {
        int krow = rbase2 + nq * 64 + fn * 16 + (lane & 15);
        if (krow > 1024) krow = 1024;
        b[fn] = *(const bf8_t*)(qrh + (long)krow * 64 + kk);
      }
#pragma unroll
      for (int fm = 0; fm < 2; ++fm)
#pragma unroll
        for (int fn = 0; fn < 4; ++fn)
          acc[fm][fn] = __builtin_amdgcn_mfma_f32_16x16x32_bf16(a[fm], b[fn], acc[fm][fn], 0, 0, 0);
    }
#pragma unroll
    for (int fm = 0; fm < 2; ++fm)
#pragma unroll
      for (int fn = 0; fn < 4; ++fn)
#pragma unroll
        for (int r = 0; r < 4; ++r)
          Tpc[mh * 32 + fm * 16 + (lane >> 4) * 4 + r][nq * 64 + fn * 16 + (lane & 15)] = f2bf(acc[fm][fn][r]);
  }

  __syncthreads();

  { // Phase 3: cc via MFMA + gather cp/pc from LDS, write scaled bf16 scores
    const int wr = w >> 1, wc = w & 1;
    f4_t acc[2][2];
#pragma unroll
    for (int i = 0; i < 2; ++i)
#pragma unroll
      for (int j = 0; j < 2; ++j) acc[i][j] = f4_t{0.f, 0.f, 0.f, 0.f};
#pragma unroll
    for (int ks = 0; ks < 2; ++ks) {
      const int kk = ks * 32 + (lane >> 4) * 8;
      bf8_t a[2], b[2];
#pragma unroll
      for (int fm = 0; fm < 2; ++fm)
        a[fm] = *(const bf8_t*)(Qb + (long)(i0 + wr * 32 + fm * 16 + (lane & 15)) * 64 + kk);
#pragma unroll
      for (int fn = 0; fn < 2; ++fn)
        b[fn] = *(const bf8_t*)(Kb + (long)(j0 + wc * 32 + fn * 16 + (lane & 15)) * 64 + kk);
#pragma unroll
      for (int fm = 0; fm < 2; ++fm)
#pragma unroll
        for (int fn = 0; fn < 2; ++fn)
          acc[fm][fn] = __builtin_amdgcn_mfma_f32_16x16x32_bf16(a[fm], b[fn], acc[fm][fn], 0, 0, 0);
    }
#pragma unroll
    for (int fm = 0; fm < 2; ++fm)
#pragma unroll
      for (int fn = 0; fn < 2; ++fn)
#pragma unroll
        for (int r = 0; r < 4; ++r) {
          const int rl = wr * 32 + fm * 16 + (lane >> 4) * 4 + r;
          const int cl = wc * 32 + fn * 16 + (lane & 15);
          const int i = i0 + rl, j = j0 + cl;
          const int d = j - i;
          int rc = d;  if (rc > 512) rc = 512;  if (rc < -512) rc = -512;  rc += 512;
          int rc2 = -d; if (rc2 > 512) rc2 = 512; if (rc2 < -512) rc2 = -512; rc2 += 512;
          float v = acc[fm][fn][r] + bf2f(Tcp[rl][rc - rbase]) + bf2f(Tpc[cl][rc2 - rbase2]);
          Sc[(long)bh * (S_ * S_) + (long)i * S_ + j] = f2bf(v * SCALE_);
        }
  }
}

// ---------------- in-place row softmax over bf16 scores -------------------
__global__ __launch_bounds__(256) void softmax_kernel(unsigned short* __restrict__ Sc) {
  unsigned short* p = Sc + (long)blockIdx.x * S_;
  const int tid = threadIdx.x;
  ushort4 u = ((const ushort4*)p)[tid];
  float f0 = bf2f(u.x), f1 = bf2f(u.y), f2 = bf2f(u.z), f3 = bf2f(u.w);
  float m = fmaxf(fmaxf(f0, f1), fmaxf(f2, f3));
#pragma unroll
  for (int off = 32; off; off >>= 1) m = fmaxf(m, __shfl_xor(m, off));
  __shared__ float redm[4];
  if ((tid & 63) == 0) redm[tid >> 6] = m;
  __syncthreads();
  m = fmaxf(fmaxf(redm[0], redm[1]), fmaxf(redm[2], redm[3]));
  float e0 = __expf(f0 - m), e1 = __expf(f1 - m), e2 = __expf(f2 - m), e3 = __expf(f3 - m);
  float s = e0 + e1 + e2 + e3;
#pragma unroll
  for (int off = 32; off; off >>= 1) s += __shfl_xor(s, off);
  __shared__ float reds[4];
  if ((tid & 63) == 0) reds[tid >> 6] = s;
  __syncthreads();
  s = reds[0] + reds[1] + reds[2] + reds[3];
  float inv = 1.0f / s;
  u.x = f2bf(e0 * inv); u.y = f2bf(e1 * inv); u.z = f2bf(e2 * inv); u.w = f2bf(e3 * inv);
  ((ushort4*)p)[tid] = u;
}

// ---------------- host launch ---------------------------------------------
extern "C" void kernel_launch(void* const* d_in, const int* in_sizes, int n_in,
                              void* d_out, int out_size, void* d_ws, size_t ws_size,
                              hipStream_t stream)
{
  const float* x   = (const float*)d_in[0];
  const float* Wq  = (const float*)d_in[1];
  const float* bq  = (const float*)d_in[2];
  const float* Wk  = (const float*)d_in[3];
  const float* bk  = (const float*)d_in[4];
  const float* Wv  = (const float*)d_in[5];
  const float* bv  = (const float*)d_in[6];
  const float* Wpq = (const float*)d_in[7];
  const float* bpq = (const float*)d_in[8];
  const float* Wpk = (const float*)d_in[9];
  const float* bpk = (const float*)d_in[10];
  const float* rel = (const float*)d_in[11];
  const float* Wo  = (const float*)d_in[12];
  const float* bo  = (const float*)d_in[13];

  char* ws = (char*)d_ws;
  auto alloc = [&](size_t bytes) { char* p = ws; ws += (bytes + 255) & ~(size_t)255; return p; };
  unsigned short* xb   = (unsigned short*)alloc((size_t)4096 * 768 * 2);
  unsigned short* Wqb  = (unsigned short*)alloc((size_t)768 * 768 * 2);
  unsigned short* Wkb  = (unsigned short*)alloc((size_t)768 * 768 * 2);
  unsigned short* Wvb  = (unsigned short*)alloc((size_t)768 * 768 * 2);
  unsigned short* Wpqb = (unsigned short*)alloc((size_t)768 * 768 * 2);
  unsigned short* Wpkb = (unsigned short*)alloc((size_t)768 * 768 * 2);
  unsigned short* Wob  = (unsigned short*)alloc((size_t)768 * 768 * 2);
  unsigned short* relb = (unsigned short*)alloc((size_t)1025 * 768 * 2);
  unsigned short* Qb   = (unsigned short*)alloc((size_t)48 * 1024 * 64 * 2);  // [B,H,S,D]
  unsigned short* Kb   = (unsigned short*)alloc((size_t)48 * 1024 * 64 * 2);  // [B,H,S,D]
  unsigned short* Vt   = (unsigned short*)alloc((size_t)48 * 64 * 1024 * 2);  // [B,H,D,S]
  unsigned short* qrb  = (unsigned short*)alloc((size_t)12 * 1025 * 64 * 2);  // [H,R,D]
  unsigned short* krb  = (unsigned short*)alloc((size_t)12 * 1025 * 64 * 2);
  unsigned short* ctx  = (unsigned short*)alloc((size_t)4096 * 768 * 2);      // [B*S, E]
  unsigned short* Sc   = (unsigned short*)alloc((size_t)48 * 1024 * 1024 * 2);

  CvtArgs ca;
  const float* srcs[8] = {x, Wq, Wk, Wv, Wpq, Wpk, Wo, rel};
  unsigned short* dsts[8] = {xb, Wqb, Wkb, Wvb, Wpqb, Wpkb, Wob, relb};
  const int nch[8] = {786432, 147456, 147456, 147456, 147456, 147456, 147456, 196800};
  int total = 0;
  for (int i = 0; i < 8; ++i) { ca.src[i] = srcs[i]; ca.dst[i] = dsts[i]; ca.nchunks[i] = nch[i]; total += nch[i]; }
  cvt_kernel<<<dim3(2048), dim3(256), 0, stream>>>(ca, total);

  dim3 blk(256);
  // content projections: [4096,768] x [768,768]^T
  gemm_bt<128, 128, MQKV><<<dim3(6, 32, 1), blk, 0, stream>>>(xb, 768, 0, Wqb, 768, 0, Qb, bq, 4096, 768, 768);
  gemm_bt<128, 128, MQKV><<<dim3(6, 32, 1), blk, 0, stream>>>(xb, 768, 0, Wkb, 768, 0, Kb, bk, 4096, 768, 768);
  gemm_bt<128, 128, MVT ><<<dim3(6, 32, 1), blk, 0, stream>>>(xb, 768, 0, Wvb, 768, 0, Vt, bv, 4096, 768, 768);
  // positional projections: [1025,768] x [768,768]^T
  gemm_bt<128, 128, MREL><<<dim3(6, 9, 1), blk, 0, stream>>>(relb, 768, 0, Wpqb, 768, 0, qrb, bpq, 1025, 768, 768);
  gemm_bt<128, 128, MREL><<<dim3(6, 9, 1), blk, 0, stream>>>(relb, 768, 0, Wpkb, 768, 0, krb, bpk, 1025, 768, 768);
  // scores + softmax
  scores_kernel<<<dim3(16, 16, 48), blk, 0, stream>>>(Qb, Kb, krb, qrb, Sc);
  softmax_kernel<<<dim3(48 * 1024), blk, 0, stream>>>(Sc);
  // PV: weights[bh] (1024x1024) x Vt[bh] (64x1024)^T -> ctx [B*S, E]
  gemm_bt<128, 64, MCTX><<<dim3(1, 8, 48), blk, 0, stream>>>(Sc, 1024, (long)1024 * 1024, Vt, 1024, 65536, ctx, nullptr, 1024, 64, 1024);
  // output projection: [4096,768] x [768,768]^T -> fp32 d_out
  gemm_bt<128, 128, MOUT><<<dim3(6, 32, 1), blk, 0, stream>>>(ctx, 768, 0, Wob, 768, 0, d_out, bo, 4096, 768, 768);

  (void)in_sizes; (void)n_in; (void)out_size; (void)ws_size;
}

// Round 2
// 466.272 us; speedup vs baseline: 1.1449x; 1.1449x over previous
//
#include <hip/hip_runtime.h>
#include <stdint.h>

typedef __attribute__((ext_vector_type(8))) short bf8_t;   // 8 x bf16 (raw bits)
typedef __attribute__((ext_vector_type(4))) float f4_t;

#define DEV __device__ __forceinline__

constexpr int S_ = 1024;
constexpr int R_ = 1025;          // 2K+1
constexpr float SCALE_ = 0.07216878364870322f;  // 1/sqrt(3*64)

DEV float bf2f(unsigned short u) { union { unsigned int i; float f; } v; v.i = ((unsigned int)u) << 16; return v.f; }
DEV unsigned short f2bf(float f) {
  union { float fv; unsigned int i; } v; v.fv = f;
  unsigned int r = v.i + 0x7FFFu + ((v.i >> 16) & 1u);
  return (unsigned short)(r >> 16);
}

// ---------------- fp32 -> bf16 bulk conversion (8 tensors, one launch) ----
struct CvtArgs { const float* src[8]; unsigned short* dst[8]; int nchunks[8]; };

__global__ __launch_bounds__(256) void cvt_kernel(CvtArgs a, int total) {
  int idx = blockIdx.x * 256 + threadIdx.x;
  int step = gridDim.x * 256;
  for (; idx < total; idx += step) {
    int c = idx, s = 0;
    while (c >= a.nchunks[s]) { c -= a.nchunks[s]; ++s; }
    float4 v = ((const float4*)a.src[s])[c];
    ushort4 o;
    o.x = f2bf(v.x); o.y = f2bf(v.y); o.z = f2bf(v.z); o.w = f2bf(v.w);
    ((ushort4*)a.dst[s])[c] = o;
  }
}

// ---------------- generic bf16 GEMM: C = A * B^T (+bias), epilogue modes --
enum { MQKV = 0, MVT = 1, MREL = 2, MCTX = 3, MOUT = 4 };

template <int BM, int BN, int MODE>
__global__ __launch_bounds__(256) void gemm_bt(
    const unsigned short* __restrict__ A, int lda, long abst,
    const unsigned short* __restrict__ B, int ldb, long bbst,
    void* __restrict__ C, const float* __restrict__ bias,
    int M, int N, int Kd)
{
  constexpr int WM = BM / 2, WN = BN / 2, FM = WM / 16, FN = WN / 16;
  __shared__ unsigned short At[BM][40];   // BK=32 + 8 pad
  __shared__ unsigned short Bt[BN][40];
  const int tid = threadIdx.x, lane = tid & 63, w = tid >> 6;
  const int wr = w >> 1, wc = w & 1;
  const int m0 = blockIdx.y * BM, n0 = blockIdx.x * BN;
  const int z = blockIdx.z;
  const unsigned short* Ab = A + (long)z * abst;
  const unsigned short* Bb = B + (long)z * bbst;

  f4_t acc[FM][FN];
#pragma unroll
  for (int i = 0; i < FM; ++i)
#pragma unroll
    for (int j = 0; j < FN; ++j) acc[i][j] = f4_t{0.f, 0.f, 0.f, 0.f};

  for (int k0 = 0; k0 < Kd; k0 += 32) {
    for (int c = tid; c < BM * 4; c += 256) {
      int row = c >> 2, c8 = (c & 3) * 8;
      int gm = m0 + row; if (gm > M - 1) gm = M - 1;
      *(int4*)&At[row][c8] = *(const int4*)(Ab + (long)gm * lda + k0 + c8);
    }
    for (int c = tid; c < BN * 4; c += 256) {
      int row = c >> 2, c8 = (c & 3) * 8;
      int gn = n0 + row; if (gn > N - 1) gn = N - 1;
      *(int4*)&Bt[row][c8] = *(const int4*)(Bb + (long)gn * ldb + k0 + c8);
    }
    __syncthreads();
    const int kk = (lane >> 4) * 8;
    bf8_t a[FM], b[FN];
#pragma unroll
    for (int fm = 0; fm < FM; ++fm) a[fm] = *(const bf8_t*)&At[wr * WM + fm * 16 + (lane & 15)][kk];
#pragma unroll
    for (int fn = 0; fn < FN; ++fn) b[fn] = *(const bf8_t*)&Bt[wc * WN + fn * 16 + (lane & 15)][kk];
#pragma unroll
    for (int fm = 0; fm < FM; ++fm)
#pragma unroll
      for (int fn = 0; fn < FN; ++fn)
        acc[fm][fn] = __builtin_amdgcn_mfma_f32_16x16x32_bf16(a[fm], b[fn], acc[fm][fn], 0, 0, 0);
    __syncthreads();
  }

#pragma unroll
  for (int fm = 0; fm < FM; ++fm)
#pragma unroll
    for (int fn = 0; fn < FN; ++fn)
#pragma unroll
      for (int r = 0; r < 4; ++r) {
        int row = wr * WM + fm * 16 + (lane >> 4) * 4 + r;
        int col = wc * WN + fn * 16 + (lane & 15);
        int m = m0 + row, n = n0 + col;
        if (m >= M || n >= N) continue;
        float v = acc[fm][fn][r];
        if (bias) v += bias[n];
        long off;
        if constexpr (MODE == MQKV)      off = (long)((m >> 10) * 12 + (n >> 6)) * 65536 + (m & 1023) * 64 + (n & 63);
        else if constexpr (MODE == MVT)  off = (long)((m >> 10) * 12 + (n >> 6)) * 65536 + (n & 63) * 1024 + (m & 1023);
        else if constexpr (MODE == MREL) off = (long)(n >> 6) * (R_ * 64) + (long)m * 64 + (n & 63);
        else if constexpr (MODE == MCTX) { int bb = z / 12, hh = z - bb * 12; off = (long)bb * 786432 + (long)m * 768 + hh * 64 + n; }
        else                             off = (long)m * 768 + n;
        if constexpr (MODE == MOUT) ((float*)C)[off] = v;
        else                        ((unsigned short*)C)[off] = f2bf(v);
      }
}

// ---------------- fused flash: scores(cc+cp+pc) + online softmax + PV -----
__global__ __launch_bounds__(256) void flash_kernel(
    const unsigned short* __restrict__ Q, const unsigned short* __restrict__ Kc,
    const unsigned short* __restrict__ kr, const unsigned short* __restrict__ qr,
    const unsigned short* __restrict__ Vt, unsigned short* __restrict__ ctx)
{
  const int bh = blockIdx.y, h = bh % 12, bb = bh / 12;
  const int i0 = blockIdx.x * 64;
  const int tid = threadIdx.x, lane = tid & 63, w = tid >> 6;
  const int g = lane >> 4, li = lane & 15;
  const unsigned short* Qb  = Q  + (long)bh * (S_ * 64);
  const unsigned short* Kb  = Kc + (long)bh * (S_ * 64);
  const unsigned short* Vb  = Vt + (long)bh * (S_ * 64);   // [64 d][1024 s]
  const unsigned short* krh = kr + (long)h * (R_ * 64);
  const unsigned short* qrh = qr + (long)h * (R_ * 64);

  __shared__ unsigned short Tcp[64][136];
  __shared__ unsigned short Tpc[64][136];
  __shared__ unsigned short Pl[64 * 64];   // XOR-swizzled, per-wave private rows

  const int mh = w & 1, nq = w >> 1;

  // hoisted Q fragments
  bf8_t q1[2][2];  // phase-1 A: rows i0 + mh*32 + fm*16 + li
#pragma unroll
  for (int fm = 0; fm < 2; ++fm)
#pragma unroll
    for (int ks = 0; ks < 2; ++ks)
      q1[fm][ks] = *(const bf8_t*)(Qb + (long)(i0 + mh * 32 + fm * 16 + li) * 64 + ks * 32 + g * 8);
  bf8_t q3[2];     // phase-3 A: rows i0 + w*16 + li
#pragma unroll
  for (int ks = 0; ks < 2; ++ks)
    q3[ks] = *(const bf8_t*)(Qb + (long)(i0 + w * 16 + li) * 64 + ks * 32 + g * 8);

  float m_r[4], l_r[4];
  f4_t acc_o[4];
#pragma unroll
  for (int r = 0; r < 4; ++r) { m_r[r] = -1e30f; l_r[r] = 0.f; }
#pragma unroll
  for (int fn = 0; fn < 4; ++fn) acc_o[fn] = f4_t{0.f, 0.f, 0.f, 0.f};

  for (int jt = 0; jt < 16; ++jt) {
    const int j0 = jt * 64;
    const int Dl = j0 - i0;
    const int rbase  = min(max(Dl - 63, -512), 512) + 512;
    const int rbase2 = min(max(-Dl - 63, -512), 512) + 512;

    { // phase 1: Tcp = Qtile(64x64) @ krWin(128x64)^T
      f4_t acc[2][4];
#pragma unroll
      for (int i = 0; i < 2; ++i)
#pragma unroll
        for (int j = 0; j < 4; ++j) acc[i][j] = f4_t{0.f, 0.f, 0.f, 0.f};
#pragma unroll
      for (int ks = 0; ks < 2; ++ks) {
        bf8_t b[4];
#pragma unroll
        for (int fn = 0; fn < 4; ++fn) {
          int krow = rbase + nq * 64 + fn * 16 + li;
          if (krow > 1024) krow = 1024;
          b[fn] = *(const bf8_t*)(krh + (long)krow * 64 + ks * 32 + g * 8);
        }
#pragma unroll
        for (int fm = 0; fm < 2; ++fm)
#pragma unroll
          for (int fn = 0; fn < 4; ++fn)
            acc[fm][fn] = __builtin_amdgcn_mfma_f32_16x16x32_bf16(q1[fm][ks], b[fn], acc[fm][fn], 0, 0, 0);
      }
#pragma unroll
      for (int fm = 0; fm < 2; ++fm)
#pragma unroll
        for (int fn = 0; fn < 4; ++fn)
#pragma unroll
          for (int r = 0; r < 4; ++r)
            Tcp[mh * 32 + fm * 16 + g * 4 + r][nq * 64 + fn * 16 + li] = f2bf(acc[fm][fn][r]);
    }

    { // phase 2: Tpc = Ktile(64x64) @ qrWin(128x64)^T
      f4_t acc[2][4];
#pragma unroll
      for (int i = 0; i < 2; ++i)
#pragma unroll
        for (int j = 0; j < 4; ++j) acc[i][j] = f4_t{0.f, 0.f, 0.f, 0.f};
#pragma unroll
      for (int ks = 0; ks < 2; ++ks) {
        bf8_t a[2], b[4];
#pragma unroll
        for (int fm = 0; fm < 2; ++fm)
          a[fm] = *(const bf8_t*)(Kb + (long)(j0 + mh * 32 + fm * 16 + li) * 64 + ks * 32 + g * 8);
#pragma unroll
        for (int fn = 0; fn < 4; ++fn) {
          int krow = rbase2 + nq * 64 + fn * 16 + li;
          if (krow > 1024) krow = 1024;
          b[fn] = *(const bf8_t*)(qrh + (long)krow * 64 + ks * 32 + g * 8);
        }
#pragma unroll
        for (int fm = 0; fm < 2; ++fm)
#pragma unroll
          for (int fn = 0; fn < 4; ++fn)
            acc[fm][fn] = __builtin_amdgcn_mfma_f32_16x16x32_bf16(a[fm], b[fn], acc[fm][fn], 0, 0, 0);
      }
#pragma unroll
      for (int fm = 0; fm < 2; ++fm)
#pragma unroll
        for (int fn = 0; fn < 4; ++fn)
#pragma unroll
          for (int r = 0; r < 4; ++r)
            Tpc[mh * 32 + fm * 16 + g * 4 + r][nq * 64 + fn * 16 + li] = f2bf(acc[fm][fn][r]);
    }

    __syncthreads();

    // phase 3: cc MFMA — wave w owns rows [w*16, w*16+16), all 64 cols
    f4_t s4[4];
#pragma unroll
    for (int fn = 0; fn < 4; ++fn) s4[fn] = f4_t{0.f, 0.f, 0.f, 0.f};
#pragma unroll
    for (int ks = 0; ks < 2; ++ks) {
      bf8_t b[4];
#pragma unroll
      for (int fn = 0; fn < 4; ++fn)
        b[fn] = *(const bf8_t*)(Kb + (long)(j0 + fn * 16 + li) * 64 + ks * 32 + g * 8);
#pragma unroll
      for (int fn = 0; fn < 4; ++fn)
        s4[fn] = __builtin_amdgcn_mfma_f32_16x16x32_bf16(q3[ks], b[fn], s4[fn], 0, 0, 0);
    }

    // gather cp/pc + scale
    float sc[4][4];
#pragma unroll
    for (int fn = 0; fn < 4; ++fn)
#pragma unroll
      for (int r = 0; r < 4; ++r) {
        const int i_loc = w * 16 + g * 4 + r;
        const int j_loc = fn * 16 + li;
        const int d = (j0 + j_loc) - (i0 + i_loc);
        int rc = d;   if (rc > 512) rc = 512;   if (rc < -512) rc = -512;   rc += 512;
        int rc2 = -d; if (rc2 > 512) rc2 = 512; if (rc2 < -512) rc2 = -512; rc2 += 512;
        float v = s4[fn][r] + bf2f(Tcp[i_loc][rc - rbase]) + bf2f(Tpc[j_loc][rc2 - rbase2]);
        sc[fn][r] = v * SCALE_;
      }

    // online softmax (rows replicated over the 16 lanes li)
    float fac[4];
#pragma unroll
    for (int r = 0; r < 4; ++r) {
      float mx = fmaxf(fmaxf(sc[0][r], sc[1][r]), fmaxf(sc[2][r], sc[3][r]));
#pragma unroll
      for (int off = 1; off < 16; off <<= 1) mx = fmaxf(mx, __shfl_xor(mx, off));
      float mnew = fmaxf(m_r[r], mx);
      fac[r] = __expf(m_r[r] - mnew);
      float rs = 0.f;
#pragma unroll
      for (int fn = 0; fn < 4; ++fn) { sc[fn][r] = __expf(sc[fn][r] - mnew); rs += sc[fn][r]; }
#pragma unroll
      for (int off = 1; off < 16; off <<= 1) rs += __shfl_xor(rs, off);
      l_r[r] = l_r[r] * fac[r] + rs;
      m_r[r] = mnew;
    }
#pragma unroll
    for (int fn = 0; fn < 4; ++fn)
#pragma unroll
      for (int r = 0; r < 4; ++r) acc_o[fn][r] *= fac[r];

    // write P (bf16) to swizzled per-wave LDS
#pragma unroll
    for (int fn = 0; fn < 4; ++fn)
#pragma unroll
      for (int r = 0; r < 4; ++r) {
        const int row = w * 16 + g * 4 + r;
        int byte = row * 128 + (fn * 16 + li) * 2;
        byte ^= (row & 7) << 4;
        *(unsigned short*)((char*)Pl + byte) = f2bf(sc[fn][r]);
      }

    // PV: acc_o += P(16x64) @ V^T(64x64)^T   (A from Pl, B = Vt rows)
#pragma unroll
    for (int ks = 0; ks < 2; ++ks) {
      const int arow = w * 16 + li;
      int abyte = arow * 128 + ks * 64 + g * 16;
      abyte ^= (arow & 7) << 4;
      bf8_t a = *(const bf8_t*)((const char*)Pl + abyte);
      bf8_t b[4];
#pragma unroll
      for (int fn2 = 0; fn2 < 4; ++fn2)
        b[fn2] = *(const bf8_t*)(Vb + (long)(fn2 * 16 + li) * 1024 + j0 + ks * 32 + g * 8);
#pragma unroll
      for (int fn2 = 0; fn2 < 4; ++fn2)
        acc_o[fn2] = __builtin_amdgcn_mfma_f32_16x16x32_bf16(a, b[fn2], acc_o[fn2], 0, 0, 0);
    }

    __syncthreads();
  }

  // epilogue: normalize, write ctx [B*S, E] bf16
#pragma unroll
  for (int fn2 = 0; fn2 < 4; ++fn2)
#pragma unroll
    for (int r = 0; r < 4; ++r) {
      const int row = i0 + w * 16 + g * 4 + r;
      const int d = fn2 * 16 + li;
      float v = acc_o[fn2][r] / l_r[r];
      ctx[((long)bb * 1024 + row) * 768 + h * 64 + d] = f2bf(v);
    }
}

// ---------------- host launch ---------------------------------------------
extern "C" void kernel_launch(void* const* d_in, const int* in_sizes, int n_in,
                              void* d_out, int out_size, void* d_ws, size_t ws_size,
                              hipStream_t stream)
{
  const float* x   = (const float*)d_in[0];
  const float* Wq  = (const float*)d_in[1];
  const float* bq  = (const float*)d_in[2];
  const float* Wk  = (const float*)d_in[3];
  const float* bk  = (const float*)d_in[4];
  const float* Wv  = (const float*)d_in[5];
  const float* bv  = (const float*)d_in[6];
  const float* Wpq = (const float*)d_in[7];
  const float* bpq = (const float*)d_in[8];
  const float* Wpk = (const float*)d_in[9];
  const float* bpk = (const float*)d_in[10];
  const float* rel = (const float*)d_in[11];
  const float* Wo  = (const float*)d_in[12];
  const float* bo  = (const float*)d_in[13];

  char* ws = (char*)d_ws;
  auto alloc = [&](size_t bytes) { char* p = ws; ws += (bytes + 255) & ~(size_t)255; return p; };
  unsigned short* xb   = (unsigned short*)alloc((size_t)4096 * 768 * 2);
  unsigned short* Wqb  = (unsigned short*)alloc((size_t)768 * 768 * 2);
  unsigned short* Wkb  = (unsigned short*)alloc((size_t)768 * 768 * 2);
  unsigned short* Wvb  = (unsigned short*)alloc((size_t)768 * 768 * 2);
  unsigned short* Wpqb = (unsigned short*)alloc((size_t)768 * 768 * 2);
  unsigned short* Wpkb = (unsigned short*)alloc((size_t)768 * 768 * 2);
  unsigned short* Wob  = (unsigned short*)alloc((size_t)768 * 768 * 2);
  unsigned short* relb = (unsigned short*)alloc((size_t)1025 * 768 * 2);
  unsigned short* Qb   = (unsigned short*)alloc((size_t)48 * 1024 * 64 * 2);  // [B,H,S,D]
  unsigned short* Kb   = (unsigned short*)alloc((size_t)48 * 1024 * 64 * 2);  // [B,H,S,D]
  unsigned short* Vt   = (unsigned short*)alloc((size_t)48 * 64 * 1024 * 2);  // [B,H,D,S]
  unsigned short* qrb  = (unsigned short*)alloc((size_t)12 * 1025 * 64 * 2);  // [H,R,D]
  unsigned short* krb  = (unsigned short*)alloc((size_t)12 * 1025 * 64 * 2);
  unsigned short* ctx  = (unsigned short*)alloc((size_t)4096 * 768 * 2);      // [B*S, E]

  CvtArgs ca;
  const float* srcs[8] = {x, Wq, Wk, Wv, Wpq, Wpk, Wo, rel};
  unsigned short* dsts[8] = {xb, Wqb, Wkb, Wvb, Wpqb, Wpkb, Wob, relb};
  const int nch[8] = {786432, 147456, 147456, 147456, 147456, 147456, 147456, 196800};
  int total = 0;
  for (int i = 0; i < 8; ++i) { ca.src[i] = srcs[i]; ca.dst[i] = dsts[i]; ca.nchunks[i] = nch[i]; total += nch[i]; }
  cvt_kernel<<<dim3(2048), dim3(256), 0, stream>>>(ca, total);

  dim3 blk(256);
  // content projections: [4096,768] x [768,768]^T  (64-row tiles -> 384 blocks)
  gemm_bt<64, 128, MQKV><<<dim3(6, 64, 1), blk, 0, stream>>>(xb, 768, 0, Wqb, 768, 0, Qb, bq, 4096, 768, 768);
  gemm_bt<64, 128, MQKV><<<dim3(6, 64, 1), blk, 0, stream>>>(xb, 768, 0, Wkb, 768, 0, Kb, bk, 4096, 768, 768);
  gemm_bt<64, 128, MVT ><<<dim3(6, 64, 1), blk, 0, stream>>>(xb, 768, 0, Wvb, 768, 0, Vt, bv, 4096, 768, 768);
  // positional projections: [1025,768] x [768,768]^T
  gemm_bt<64, 128, MREL><<<dim3(6, 17, 1), blk, 0, stream>>>(relb, 768, 0, Wpqb, 768, 0, qrb, bpq, 1025, 768, 768);
  gemm_bt<64, 128, MREL><<<dim3(6, 17, 1), blk, 0, stream>>>(relb, 768, 0, Wpkb, 768, 0, krb, bpk, 1025, 768, 768);
  // fused scores + softmax + PV
  flash_kernel<<<dim3(16, 48), blk, 0, stream>>>(Qb, Kb, krb, qrb, Vt, ctx);
  // output projection: [4096,768] x [768,768]^T -> fp32 d_out
  gemm_bt<64, 128, MOUT><<<dim3(6, 64, 1), blk, 0, stream>>>(ctx, 768, 0, Wob, 768, 0, d_out, bo, 4096, 768, 768);

  (void)in_sizes; (void)n_in; (void)out_size; (void)ws_size;
}

// Round 3
// 362.458 us; speedup vs baseline: 1.4728x; 1.2864x over previous
//
#include <hip/hip_runtime.h>
#include <stdint.h>

typedef __attribute__((ext_vector_type(8))) short bf8_t;   // 8 x bf16 (raw bits)
typedef __attribute__((ext_vector_type(4))) float f4_t;

#define DEV __device__ __forceinline__

constexpr int S_ = 1024;
constexpr int R_ = 1025;          // 2K+1
constexpr float SCALE_ = 0.07216878364870322f;  // 1/sqrt(3*64)

DEV float bf2f(unsigned short u) { union { unsigned int i; float f; } v; v.i = ((unsigned int)u) << 16; return v.f; }
DEV unsigned short f2bf(float f) {
  union { float fv; unsigned int i; } v; v.fv = f;
  unsigned int r = v.i + 0x7FFFu + ((v.i >> 16) & 1u);
  return (unsigned short)(r >> 16);
}

DEV void gll16(const unsigned short* g, unsigned short* l) {
  __builtin_amdgcn_global_load_lds(
      (const __attribute__((address_space(1))) unsigned int*)g,
      (__attribute__((address_space(3))) unsigned int*)l, 16, 0, 0);
}

// ---------------- fp32 -> bf16 bulk conversion (8 tensors, one launch) ----
struct CvtArgs { const float* src[8]; unsigned short* dst[8]; int nchunks[8]; };

__global__ __launch_bounds__(256) void cvt_kernel(CvtArgs a, int total) {
  int idx = blockIdx.x * 256 + threadIdx.x;
  int step = gridDim.x * 256;
  for (; idx < total; idx += step) {
    int c = idx, s = 0;
    while (c >= a.nchunks[s]) { c -= a.nchunks[s]; ++s; }
    float4 v = ((const float4*)a.src[s])[c];
    ushort4 o;
    o.x = f2bf(v.x); o.y = f2bf(v.y); o.z = f2bf(v.z); o.w = f2bf(v.w);
    ((ushort4*)a.dst[s])[c] = o;
  }
}

// ---------------- generic bf16 GEMM: C = A * B^T (+bias), epilogue modes --
enum { MQKV = 0, MVT = 1, MREL = 2, MCTX = 3, MOUT = 4, MCP = 5 };

template <int BM, int BN, int MODE>
__global__ __launch_bounds__(256) void gemm_bt(
    const unsigned short* __restrict__ A, int lda, long abst,
    const unsigned short* __restrict__ B, int ldb, long bbst, int bmod,
    void* __restrict__ C, const float* __restrict__ bias,
    int M, int N, int Kd)
{
  constexpr int WM = BM / 2, WN = BN / 2, FM = WM / 16, FN = WN / 16;
  __shared__ unsigned short At[BM][40];   // BK=32 + 8 pad
  __shared__ unsigned short Bt[BN][40];
  const int tid = threadIdx.x, lane = tid & 63, w = tid >> 6;
  const int wr = w >> 1, wc = w & 1;
  const int m0 = blockIdx.y * BM, n0 = blockIdx.x * BN;
  const int z = blockIdx.z;
  const int zb = bmod > 0 ? (z % bmod) : z;
  const unsigned short* Ab = A + (long)z * abst;
  const unsigned short* Bb = B + (long)zb * bbst;

  f4_t acc[FM][FN];
#pragma unroll
  for (int i = 0; i < FM; ++i)
#pragma unroll
    for (int j = 0; j < FN; ++j) acc[i][j] = f4_t{0.f, 0.f, 0.f, 0.f};

  for (int k0 = 0; k0 < Kd; k0 += 32) {
    for (int c = tid; c < BM * 4; c += 256) {
      int row = c >> 2, c8 = (c & 3) * 8;
      int gm = m0 + row; if (gm > M - 1) gm = M - 1;
      *(int4*)&At[row][c8] = *(const int4*)(Ab + (long)gm * lda + k0 + c8);
    }
    for (int c = tid; c < BN * 4; c += 256) {
      int row = c >> 2, c8 = (c & 3) * 8;
      int gn = n0 + row; if (gn > N - 1) gn = N - 1;
      *(int4*)&Bt[row][c8] = *(const int4*)(Bb + (long)gn * ldb + k0 + c8);
    }
    __syncthreads();
    const int kk = (lane >> 4) * 8;
    bf8_t a[FM], b[FN];
#pragma unroll
    for (int fm = 0; fm < FM; ++fm) a[fm] = *(const bf8_t*)&At[wr * WM + fm * 16 + (lane & 15)][kk];
#pragma unroll
    for (int fn = 0; fn < FN; ++fn) b[fn] = *(const bf8_t*)&Bt[wc * WN + fn * 16 + (lane & 15)][kk];
#pragma unroll
    for (int fm = 0; fm < FM; ++fm)
#pragma unroll
      for (int fn = 0; fn < FN; ++fn)
        acc[fm][fn] = __builtin_amdgcn_mfma_f32_16x16x32_bf16(a[fm], b[fn], acc[fm][fn], 0, 0, 0);
    __syncthreads();
  }

#pragma unroll
  for (int fm = 0; fm < FM; ++fm)
#pragma unroll
    for (int fn = 0; fn < FN; ++fn)
#pragma unroll
      for (int r = 0; r < 4; ++r) {
        int row = wr * WM + fm * 16 + (lane >> 4) * 4 + r;
        int col = wc * WN + fn * 16 + (lane & 15);
        int m = m0 + row, n = n0 + col;
        if (m >= M || n >= N) continue;
        float v = acc[fm][fn][r];
        if (bias) v += bias[n];
        long off;
        if constexpr (MODE == MQKV)      off = (long)((m >> 10) * 12 + (n >> 6)) * 65536 + (m & 1023) * 64 + (n & 63);
        else if constexpr (MODE == MVT)  off = (long)((m >> 10) * 12 + (n >> 6)) * 65536 + (n & 63) * 1024 + (m & 1023);
        else if constexpr (MODE == MREL) off = (long)(n >> 6) * (R_ * 64) + (long)m * 64 + (n & 63);
        else if constexpr (MODE == MCTX) { int bb = z / 12, hh = z - bb * 12; off = (long)bb * 786432 + (long)m * 768 + hh * 64 + n; }
        else if constexpr (MODE == MCP)  off = (long)z * ((long)S_ * R_) + (long)m * R_ + n;
        else                             off = (long)m * 768 + n;
        if constexpr (MODE == MOUT) ((float*)C)[off] = v;
        else                        ((unsigned short*)C)[off] = f2bf(v);
      }
}

// ---------------- fused flash: cc + cp(gather) + pc(on-chip) + softmax + PV
__global__ __launch_bounds__(256) void flash_kernel(
    const unsigned short* __restrict__ Q, const unsigned short* __restrict__ Kc,
    const unsigned short* __restrict__ qr, const unsigned short* __restrict__ Vt,
    const unsigned short* __restrict__ cp, unsigned short* __restrict__ ctx)
{
  const int bh = blockIdx.y, h = bh % 12, bb = bh / 12;
  const int i0 = blockIdx.x * 64;
  const int tid = threadIdx.x, lane = tid & 63, w = tid >> 6;
  const int g = lane >> 4, li = lane & 15;
  const unsigned short* Qb  = Q  + (long)bh * (S_ * 64);
  const unsigned short* Kb  = Kc + (long)bh * (S_ * 64);
  const unsigned short* Vb  = Vt + (long)bh * (S_ * 64);   // [64 d][1024 s]
  const unsigned short* qrh = qr + (long)h * (R_ * 64);
  const unsigned short* cpb = cp + (long)bh * ((long)S_ * R_);

  __shared__ unsigned short Kt[2][4096];   // [buf] 64 rows x 64el, XOR-swizzled chunks
  __shared__ unsigned short Vl[2][4096];
  __shared__ unsigned short Tpc[64][136];
  __shared__ unsigned short Pl[4096];      // per-wave private P rows, XOR-swizzled

  const int mh = w & 1, nq = w >> 1;

  // stage K-tile + V-tile for tile jt into buffer buf (source-preswizzled)
  const int sr0 = w * 8 + (lane >> 3);
  const int scc = (lane & 7) ^ (sr0 & 7);      // same for sr0 and sr0+32
  auto stage = [&](int buf, int jt) {
    const int j0n = jt * 64;
    gll16(Kb + (long)(j0n + sr0) * 64 + scc * 8,      &Kt[buf][w * 512 + lane * 8]);
    gll16(Kb + (long)(j0n + sr0 + 32) * 64 + scc * 8, &Kt[buf][w * 512 + 2048 + lane * 8]);
    gll16(Vb + (long)sr0 * 1024 + j0n + scc * 8,        &Vl[buf][w * 512 + lane * 8]);
    gll16(Vb + (long)(sr0 + 32) * 1024 + j0n + scc * 8, &Vl[buf][w * 512 + 2048 + lane * 8]);
  };
  auto chunk = [&](const unsigned short* base, int row, int ck) -> const bf8_t* {
    return (const bf8_t*)((const char*)base + row * 128 + ((ck ^ (row & 7)) << 4));
  };

  // hoisted Q fragments (wave w owns rows i0 + w*16 .. +16)
  bf8_t q3[2];
#pragma unroll
  for (int ks = 0; ks < 2; ++ks)
    q3[ks] = *(const bf8_t*)(Qb + (long)(i0 + w * 16 + li) * 64 + ks * 32 + g * 8);

  float m_r[4], l_r[4];
  f4_t acc_o[4];
#pragma unroll
  for (int r = 0; r < 4; ++r) { m_r[r] = -1e30f; l_r[r] = 0.f; }
#pragma unroll
  for (int fn = 0; fn < 4; ++fn) acc_o[fn] = f4_t{0.f, 0.f, 0.f, 0.f};

  stage(0, 0);

  for (int jt = 0; jt < 16; ++jt) {
    const int cur = jt & 1;
    const int j0 = jt * 64;
    const int Dl = j0 - i0;
    const int rbase2 = min(max(-Dl - 63, -512), 512) + 512;

    asm volatile("s_waitcnt vmcnt(0)" ::: "memory");
    __builtin_amdgcn_s_barrier();
    if (jt + 1 < 16) stage(cur ^ 1, jt + 1);

    { // Tpc = Ktile(64x64) @ qrWin(128x64)^T  (A from swizzled LDS, B global)
      f4_t acc[2][4];
#pragma unroll
      for (int i = 0; i < 2; ++i)
#pragma unroll
        for (int j = 0; j < 4; ++j) acc[i][j] = f4_t{0.f, 0.f, 0.f, 0.f};
#pragma unroll
      for (int ks = 0; ks < 2; ++ks) {
        bf8_t a[2], b[4];
#pragma unroll
        for (int fm = 0; fm < 2; ++fm)
          a[fm] = *chunk(Kt[cur], mh * 32 + fm * 16 + li, ks * 4 + g);
#pragma unroll
        for (int fn = 0; fn < 4; ++fn) {
          int krow = rbase2 + nq * 64 + fn * 16 + li;
          if (krow > 1024) krow = 1024;
          b[fn] = *(const bf8_t*)(qrh + (long)krow * 64 + ks * 32 + g * 8);
        }
#pragma unroll
        for (int fm = 0; fm < 2; ++fm)
#pragma unroll
          for (int fn = 0; fn < 4; ++fn)
            acc[fm][fn] = __builtin_amdgcn_mfma_f32_16x16x32_bf16(a[fm], b[fn], acc[fm][fn], 0, 0, 0);
      }
#pragma unroll
      for (int fm = 0; fm < 2; ++fm)
#pragma unroll
        for (int fn = 0; fn < 4; ++fn)
#pragma unroll
          for (int r = 0; r < 4; ++r)
            Tpc[mh * 32 + fm * 16 + g * 4 + r][nq * 64 + fn * 16 + li] = f2bf(acc[fm][fn][r]);
    }

    asm volatile("s_waitcnt lgkmcnt(0)" ::: "memory");
    __builtin_amdgcn_s_barrier();

    // cc MFMA — wave w: rows [w*16, w*16+16), all 64 cols, K from swizzled LDS
    f4_t s4[4];
#pragma unroll
    for (int fn = 0; fn < 4; ++fn) s4[fn] = f4_t{0.f, 0.f, 0.f, 0.f};
#pragma unroll
    for (int ks = 0; ks < 2; ++ks) {
      bf8_t b[4];
#pragma unroll
      for (int fn = 0; fn < 4; ++fn)
        b[fn] = *chunk(Kt[cur], fn * 16 + li, ks * 4 + g);
#pragma unroll
      for (int fn = 0; fn < 4; ++fn)
        s4[fn] = __builtin_amdgcn_mfma_f32_16x16x32_bf16(q3[ks], b[fn], s4[fn], 0, 0, 0);
    }

    // gather: cp from global table, pc from Tpc LDS; scale
    float sc[4][4];
#pragma unroll
    for (int fn = 0; fn < 4; ++fn)
#pragma unroll
      for (int r = 0; r < 4; ++r) {
        const int i_loc = w * 16 + g * 4 + r;
        const int j_loc = fn * 16 + li;
        const int d = (j0 + j_loc) - (i0 + i_loc);
        int rc = d;   if (rc > 512) rc = 512;   if (rc < -512) rc = -512;   rc += 512;
        int rc2 = -d; if (rc2 > 512) rc2 = 512; if (rc2 < -512) rc2 = -512; rc2 += 512;
        float v = s4[fn][r] + bf2f(cpb[(long)(i0 + i_loc) * R_ + rc])
                            + bf2f(Tpc[j_loc][rc2 - rbase2]);
        sc[fn][r] = v * SCALE_;
      }

    // online softmax (rows replicated over 16 lanes li)
    float fac[4];
#pragma unroll
    for (int r = 0; r < 4; ++r) {
      float mx = fmaxf(fmaxf(sc[0][r], sc[1][r]), fmaxf(sc[2][r], sc[3][r]));
#pragma unroll
      for (int off = 1; off < 16; off <<= 1) mx = fmaxf(mx, __shfl_xor(mx, off));
      float mnew = fmaxf(m_r[r], mx);
      fac[r] = __expf(m_r[r] - mnew);
      float rs = 0.f;
#pragma unroll
      for (int fn = 0; fn < 4; ++fn) { sc[fn][r] = __expf(sc[fn][r] - mnew); rs += sc[fn][r]; }
#pragma unroll
      for (int off = 1; off < 16; off <<= 1) rs += __shfl_xor(rs, off);
      l_r[r] = l_r[r] * fac[r] + rs;
      m_r[r] = mnew;
    }
#pragma unroll
    for (int fn = 0; fn < 4; ++fn)
#pragma unroll
      for (int r = 0; r < 4; ++r) acc_o[fn][r] *= fac[r];

    // write P (bf16) to swizzled per-wave LDS
#pragma unroll
    for (int fn = 0; fn < 4; ++fn)
#pragma unroll
      for (int r = 0; r < 4; ++r) {
        const int row = w * 16 + g * 4 + r;
        int byte = row * 128 + (fn * 16 + li) * 2;
        byte ^= (row & 7) << 4;
        *(unsigned short*)((char*)Pl + byte) = f2bf(sc[fn][r]);
      }

    // PV: acc_o += P(16x64) @ V^T  (A from Pl, B from swizzled V_lds)
#pragma unroll
    for (int ks = 0; ks < 2; ++ks) {
      const int arow = w * 16 + li;
      int abyte = arow * 128 + ks * 64 + g * 16;
      abyte ^= (arow & 7) << 4;
      bf8_t a = *(const bf8_t*)((const char*)Pl + abyte);
      bf8_t b[4];
#pragma unroll
      for (int fn2 = 0; fn2 < 4; ++fn2)
        b[fn2] = *chunk(Vl[cur], fn2 * 16 + li, ks * 4 + g);
#pragma unroll
      for (int fn2 = 0; fn2 < 4; ++fn2)
        acc_o[fn2] = __builtin_amdgcn_mfma_f32_16x16x32_bf16(a, b[fn2], acc_o[fn2], 0, 0, 0);
    }
  }

  // epilogue: normalize, write ctx [B*S, E] bf16
#pragma unroll
  for (int fn2 = 0; fn2 < 4; ++fn2)
#pragma unroll
    for (int r = 0; r < 4; ++r) {
      const int row = i0 + w * 16 + g * 4 + r;
      const int d = fn2 * 16 + li;
      float v = acc_o[fn2][r] / l_r[r];
      ctx[((long)bb * 1024 + row) * 768 + h * 64 + d] = f2bf(v);
    }
}

// ---------------- host launch ---------------------------------------------
extern "C" void kernel_launch(void* const* d_in, const int* in_sizes, int n_in,
                              void* d_out, int out_size, void* d_ws, size_t ws_size,
                              hipStream_t stream)
{
  const float* x   = (const float*)d_in[0];
  const float* Wq  = (const float*)d_in[1];
  const float* bq  = (const float*)d_in[2];
  const float* Wk  = (const float*)d_in[3];
  const float* bk  = (const float*)d_in[4];
  const float* Wv  = (const float*)d_in[5];
  const float* bv  = (const float*)d_in[6];
  const float* Wpq = (const float*)d_in[7];
  const float* bpq = (const float*)d_in[8];
  const float* Wpk = (const float*)d_in[9];
  const float* bpk = (const float*)d_in[10];
  const float* rel = (const float*)d_in[11];
  const float* Wo  = (const float*)d_in[12];
  const float* bo  = (const float*)d_in[13];

  char* ws = (char*)d_ws;
  auto alloc = [&](size_t bytes) { char* p = ws; ws += (bytes + 255) & ~(size_t)255; return p; };
  unsigned short* xb   = (unsigned short*)alloc((size_t)4096 * 768 * 2);
  unsigned short* Wqb  = (unsigned short*)alloc((size_t)768 * 768 * 2);
  unsigned short* Wkb  = (unsigned short*)alloc((size_t)768 * 768 * 2);
  unsigned short* Wvb  = (unsigned short*)alloc((size_t)768 * 768 * 2);
  unsigned short* Wpqb = (unsigned short*)alloc((size_t)768 * 768 * 2);
  unsigned short* Wpkb = (unsigned short*)alloc((size_t)768 * 768 * 2);
  unsigned short* Wob  = (unsigned short*)alloc((size_t)768 * 768 * 2);
  unsigned short* relb = (unsigned short*)alloc((size_t)1025 * 768 * 2);
  unsigned short* Qb   = (unsigned short*)alloc((size_t)48 * 1024 * 64 * 2);  // [B,H,S,D]
  unsigned short* Kb   = (unsigned short*)alloc((size_t)48 * 1024 * 64 * 2);  // [B,H,S,D]
  unsigned short* Vt   = (unsigned short*)alloc((size_t)48 * 64 * 1024 * 2);  // [B,H,D,S]
  unsigned short* qrb  = (unsigned short*)alloc((size_t)12 * 1025 * 64 * 2);  // [H,R,D]
  unsigned short* krb  = (unsigned short*)alloc((size_t)12 * 1025 * 64 * 2);
  unsigned short* ctx  = (unsigned short*)alloc((size_t)4096 * 768 * 2);      // [B*S, E]
  unsigned short* cpt  = (unsigned short*)alloc((size_t)48 * 1024 * 1025 * 2);// [BH,S,R]

  CvtArgs ca;
  const float* srcs[8] = {x, Wq, Wk, Wv, Wpq, Wpk, Wo, rel};
  unsigned short* dsts[8] = {xb, Wqb, Wkb, Wvb, Wpqb, Wpkb, Wob, relb};
  const int nch[8] = {786432, 147456, 147456, 147456, 147456, 147456, 147456, 196800};
  int total = 0;
  for (int i = 0; i < 8; ++i) { ca.src[i] = srcs[i]; ca.dst[i] = dsts[i]; ca.nchunks[i] = nch[i]; total += nch[i]; }
  cvt_kernel<<<dim3(2048), dim3(256), 0, stream>>>(ca, total);

  dim3 blk(256);
  // content projections: [4096,768] x [768,768]^T
  gemm_bt<64, 128, MQKV><<<dim3(6, 64, 1), blk, 0, stream>>>(xb, 768, 0, Wqb, 768, 0, 0, Qb, bq, 4096, 768, 768);
  gemm_bt<64, 128, MQKV><<<dim3(6, 64, 1), blk, 0, stream>>>(xb, 768, 0, Wkb, 768, 0, 0, Kb, bk, 4096, 768, 768);
  gemm_bt<64, 128, MVT ><<<dim3(6, 64, 1), blk, 0, stream>>>(xb, 768, 0, Wvb, 768, 0, 0, Vt, bv, 4096, 768, 768);
  // positional projections: [1025,768] x [768,768]^T
  gemm_bt<64, 128, MREL><<<dim3(6, 17, 1), blk, 0, stream>>>(relb, 768, 0, Wpqb, 768, 0, 0, qrb, bpq, 1025, 768, 768);
  gemm_bt<64, 128, MREL><<<dim3(6, 17, 1), blk, 0, stream>>>(relb, 768, 0, Wpkb, 768, 0, 0, krb, bpk, 1025, 768, 768);
  // cp_score precompute: per bh, Q[bh] (1024x64) x krb[h] (1025x64)^T -> [BH,S,R]
  gemm_bt<64, 128, MCP><<<dim3(9, 16, 48), blk, 0, stream>>>(Qb, 64, 65536, krb, 64, (long)R_ * 64, 12, cpt, nullptr, 1024, 1025, 64);
  // fused scores + softmax + PV
  flash_kernel<<<dim3(16, 48), blk, 0, stream>>>(Qb, Kb, qrb, Vt, cpt, ctx);
  // output projection: [4096,768] x [768,768]^T -> fp32 d_out
  gemm_bt<64, 128, MOUT><<<dim3(6, 64, 1), blk, 0, stream>>>(ctx, 768, 0, Wob, 768, 0, 0, d_out, bo, 4096, 768, 768);

  (void)in_sizes; (void)n_in; (void)out_size; (void)ws_size;
}

// Round 4
// 359.416 us; speedup vs baseline: 1.4853x; 1.0085x over previous
//
#include <hip/hip_runtime.h>
#include <stdint.h>

typedef __attribute__((ext_vector_type(8))) short bf8_t;   // 8 x bf16 (raw bits)
typedef __attribute__((ext_vector_type(4))) float f4_t;

#define DEV __device__ __forceinline__

constexpr int S_ = 1024;
constexpr int R_ = 1025;          // 2K+1
constexpr float SCALE_ = 0.07216878364870322f;  // 1/sqrt(3*64)

DEV float bf2f(unsigned short u) { union { unsigned int i; float f; } v; v.i = ((unsigned int)u) << 16; return v.f; }
DEV unsigned short f2bf(float f) {
  union { float fv; unsigned int i; } v; v.fv = f;
  unsigned int r = v.i + 0x7FFFu + ((v.i >> 16) & 1u);
  return (unsigned short)(r >> 16);
}

DEV void gll16(const unsigned short* g, unsigned short* l) {
  __builtin_amdgcn_global_load_lds(
      (const __attribute__((address_space(1))) unsigned int*)g,
      (__attribute__((address_space(3))) unsigned int*)l, 16, 0, 0);
}

// ---------------- fp32 -> bf16 bulk conversion (8 tensors, one launch) ----
struct CvtArgs { const float* src[8]; unsigned short* dst[8]; int nchunks[8]; };

__global__ __launch_bounds__(256) void cvt_kernel(CvtArgs a, int total) {
  int idx = blockIdx.x * 256 + threadIdx.x;
  int step = gridDim.x * 256;
  for (; idx < total; idx += step) {
    int c = idx, s = 0;
    while (c >= a.nchunks[s]) { c -= a.nchunks[s]; ++s; }
    float4 v = ((const float4*)a.src[s])[c];
    ushort4 o;
    o.x = f2bf(v.x); o.y = f2bf(v.y); o.z = f2bf(v.z); o.w = f2bf(v.w);
    ((ushort4*)a.dst[s])[c] = o;
  }
}

// ---------------- generic bf16 GEMM: C = A * B^T (+bias), epilogue modes --
enum { MQKV = 0, MVT = 1, MREL = 2, MCTX = 3, MOUT = 4 };

template <int BM, int BN, int MODE>
__global__ __launch_bounds__(256) void gemm_bt(
    const unsigned short* __restrict__ A, int lda, long abst,
    const unsigned short* __restrict__ B, int ldb, long bbst,
    void* __restrict__ C, const float* __restrict__ bias,
    int M, int N, int Kd)
{
  constexpr int WM = BM / 2, WN = BN / 2, FM = WM / 16, FN = WN / 16;
  __shared__ unsigned short At[BM][40];   // BK=32 + 8 pad
  __shared__ unsigned short Bt[BN][40];
  const int tid = threadIdx.x, lane = tid & 63, w = tid >> 6;
  const int wr = w >> 1, wc = w & 1;
  const int m0 = blockIdx.y * BM, n0 = blockIdx.x * BN;
  const int z = blockIdx.z;
  const unsigned short* Ab = A + (long)z * abst;
  const unsigned short* Bb = B + (long)z * bbst;

  f4_t acc[FM][FN];
#pragma unroll
  for (int i = 0; i < FM; ++i)
#pragma unroll
    for (int j = 0; j < FN; ++j) acc[i][j] = f4_t{0.f, 0.f, 0.f, 0.f};

  for (int k0 = 0; k0 < Kd; k0 += 32) {
    for (int c = tid; c < BM * 4; c += 256) {
      int row = c >> 2, c8 = (c & 3) * 8;
      int gm = m0 + row; if (gm > M - 1) gm = M - 1;
      *(int4*)&At[row][c8] = *(const int4*)(Ab + (long)gm * lda + k0 + c8);
    }
    for (int c = tid; c < BN * 4; c += 256) {
      int row = c >> 2, c8 = (c & 3) * 8;
      int gn = n0 + row; if (gn > N - 1) gn = N - 1;
      *(int4*)&Bt[row][c8] = *(const int4*)(Bb + (long)gn * ldb + k0 + c8);
    }
    __syncthreads();
    const int kk = (lane >> 4) * 8;
    bf8_t a[FM], b[FN];
#pragma unroll
    for (int fm = 0; fm < FM; ++fm) a[fm] = *(const bf8_t*)&At[wr * WM + fm * 16 + (lane & 15)][kk];
#pragma unroll
    for (int fn = 0; fn < FN; ++fn) b[fn] = *(const bf8_t*)&Bt[wc * WN + fn * 16 + (lane & 15)][kk];
#pragma unroll
    for (int fm = 0; fm < FM; ++fm)
#pragma unroll
      for (int fn = 0; fn < FN; ++fn)
        acc[fm][fn] = __builtin_amdgcn_mfma_f32_16x16x32_bf16(a[fm], b[fn], acc[fm][fn], 0, 0, 0);
    __syncthreads();
  }

#pragma unroll
  for (int fm = 0; fm < FM; ++fm)
#pragma unroll
    for (int fn = 0; fn < FN; ++fn)
#pragma unroll
      for (int r = 0; r < 4; ++r) {
        int row = wr * WM + fm * 16 + (lane >> 4) * 4 + r;
        int col = wc * WN + fn * 16 + (lane & 15);
        int m = m0 + row, n = n0 + col;
        if (m >= M || n >= N) continue;
        float v = acc[fm][fn][r];
        if (bias) v += bias[n];
        long off;
        if constexpr (MODE == MQKV)      off = (long)((m >> 10) * 12 + (n >> 6)) * 65536 + (m & 1023) * 64 + (n & 63);
        else if constexpr (MODE == MVT)  off = (long)((m >> 10) * 12 + (n >> 6)) * 65536 + (n & 63) * 1024 + (m & 1023);
        else if constexpr (MODE == MREL) off = (long)(n >> 6) * (R_ * 64) + (long)m * 64 + (n & 63);
        else if constexpr (MODE == MCTX) { int bb = z / 12, hh = z - bb * 12; off = (long)bb * 786432 + (long)m * 768 + hh * 64 + n; }
        else                             off = (long)m * 768 + n;
        if constexpr (MODE == MOUT) ((float*)C)[off] = v;
        else                        ((unsigned short*)C)[off] = f2bf(v);
      }
}

// ------- fused flash: cc + cp(on-chip) + pc(on-chip) + softmax + PV -------
__global__ __launch_bounds__(256) void flash_kernel(
    const unsigned short* __restrict__ Q, const unsigned short* __restrict__ Kc,
    const unsigned short* __restrict__ kr, const unsigned short* __restrict__ qr,
    const unsigned short* __restrict__ Vt, unsigned short* __restrict__ ctx)
{
  const int bh = blockIdx.y, h = bh % 12, bb = bh / 12;
  const int i0 = blockIdx.x * 64;
  const int tid = threadIdx.x, lane = tid & 63, w = tid >> 6;
  const int g = lane >> 4, li = lane & 15;
  const unsigned short* Qb  = Q  + (long)bh * (S_ * 64);
  const unsigned short* Kb  = Kc + (long)bh * (S_ * 64);
  const unsigned short* Vb  = Vt + (long)bh * (S_ * 64);   // [64 d][1024 s]
  const unsigned short* krh = kr + (long)h * (R_ * 64);
  const unsigned short* qrh = qr + (long)h * (R_ * 64);

  __shared__ unsigned short Kt[2][4096];   // [buf] 64 rows x 64el, XOR-swizzled chunks
  __shared__ unsigned short Vl[2][4096];
  __shared__ unsigned short TcpL[64][136];
  __shared__ unsigned short Tpc[64][136];
  __shared__ unsigned short Pl[4096];      // per-wave private P rows, XOR-swizzled

  const int mh = w & 1, nq = w >> 1;

  // stage K-tile + V-tile for tile jt into buffer buf (source-preswizzled)
  const int sr0 = w * 8 + (lane >> 3);
  const int scc = (lane & 7) ^ (sr0 & 7);      // same for sr0 and sr0+32
  auto stage = [&](int buf, int jt) {
    const int j0n = jt * 64;
    gll16(Kb + (long)(j0n + sr0) * 64 + scc * 8,      &Kt[buf][w * 512 + lane * 8]);
    gll16(Kb + (long)(j0n + sr0 + 32) * 64 + scc * 8, &Kt[buf][w * 512 + 2048 + lane * 8]);
    gll16(Vb + (long)sr0 * 1024 + j0n + scc * 8,        &Vl[buf][w * 512 + lane * 8]);
    gll16(Vb + (long)(sr0 + 32) * 1024 + j0n + scc * 8, &Vl[buf][w * 512 + 2048 + lane * 8]);
  };
  auto chunk = [&](const unsigned short* base, int row, int ck) -> const bf8_t* {
    return (const bf8_t*)((const char*)base + row * 128 + ((ck ^ (row & 7)) << 4));
  };

  // hoisted Q fragments
  bf8_t q1[2][2];  // Tcp A: rows i0 + mh*32 + fm*16 + li
#pragma unroll
  for (int fm = 0; fm < 2; ++fm)
#pragma unroll
    for (int ks = 0; ks < 2; ++ks)
      q1[fm][ks] = *(const bf8_t*)(Qb + (long)(i0 + mh * 32 + fm * 16 + li) * 64 + ks * 32 + g * 8);
  bf8_t q3[2];     // cc A: rows i0 + w*16 + li
#pragma unroll
  for (int ks = 0; ks < 2; ++ks)
    q3[ks] = *(const bf8_t*)(Qb + (long)(i0 + w * 16 + li) * 64 + ks * 32 + g * 8);

  float m_r[4], l_r[4];
  f4_t acc_o[4];
#pragma unroll
  for (int r = 0; r < 4; ++r) { m_r[r] = -1e30f; l_r[r] = 0.f; }
#pragma unroll
  for (int fn = 0; fn < 4; ++fn) acc_o[fn] = f4_t{0.f, 0.f, 0.f, 0.f};

  stage(0, 0);

  for (int jt = 0; jt < 16; ++jt) {
    const int cur = jt & 1;
    const int j0 = jt * 64;
    const int Dl = j0 - i0;
    const int rbase  = min(max(Dl - 63, -512), 512) + 512;
    const int rbase2 = min(max(-Dl - 63, -512), 512) + 512;

    asm volatile("s_waitcnt vmcnt(0)" ::: "memory");
    __builtin_amdgcn_s_barrier();
    if (jt + 1 < 16) stage(cur ^ 1, jt + 1);

    { // Tcp = Qtile(64x64) @ krWin(128x64)^T  (A hoisted, B global/L2)
      f4_t acc[2][4];
#pragma unroll
      for (int i = 0; i < 2; ++i)
#pragma unroll
        for (int j = 0; j < 4; ++j) acc[i][j] = f4_t{0.f, 0.f, 0.f, 0.f};
#pragma unroll
      for (int ks = 0; ks < 2; ++ks) {
        bf8_t b[4];
#pragma unroll
        for (int fn = 0; fn < 4; ++fn) {
          int krow = rbase + nq * 64 + fn * 16 + li;
          if (krow > 1024) krow = 1024;
          b[fn] = *(const bf8_t*)(krh + (long)krow * 64 + ks * 32 + g * 8);
        }
#pragma unroll
        for (int fm = 0; fm < 2; ++fm)
#pragma unroll
          for (int fn = 0; fn < 4; ++fn)
            acc[fm][fn] = __builtin_amdgcn_mfma_f32_16x16x32_bf16(q1[fm][ks], b[fn], acc[fm][fn], 0, 0, 0);
      }
#pragma unroll
      for (int fm = 0; fm < 2; ++fm)
#pragma unroll
        for (int fn = 0; fn < 4; ++fn)
#pragma unroll
          for (int r = 0; r < 4; ++r)
            TcpL[mh * 32 + fm * 16 + g * 4 + r][nq * 64 + fn * 16 + li] = f2bf(acc[fm][fn][r]);
    }

    { // Tpc = Ktile(64x64) @ qrWin(128x64)^T  (A from swizzled LDS, B global/L2)
      f4_t acc[2][4];
#pragma unroll
      for (int i = 0; i < 2; ++i)
#pragma unroll
        for (int j = 0; j < 4; ++j) acc[i][j] = f4_t{0.f, 0.f, 0.f, 0.f};
#pragma unroll
      for (int ks = 0; ks < 2; ++ks) {
        bf8_t a[2], b[4];
#pragma unroll
        for (int fm = 0; fm < 2; ++fm)
          a[fm] = *chunk(Kt[cur], mh * 32 + fm * 16 + li, ks * 4 + g);
#pragma unroll
        for (int fn = 0; fn < 4; ++fn) {
          int krow = rbase2 + nq * 64 + fn * 16 + li;
          if (krow > 1024) krow = 1024;
          b[fn] = *(const bf8_t*)(qrh + (long)krow * 64 + ks * 32 + g * 8);
        }
#pragma unroll
        for (int fm = 0; fm < 2; ++fm)
#pragma unroll
          for (int fn = 0; fn < 4; ++fn)
            acc[fm][fn] = __builtin_amdgcn_mfma_f32_16x16x32_bf16(a[fm], b[fn], acc[fm][fn], 0, 0, 0);
      }
#pragma unroll
      for (int fm = 0; fm < 2; ++fm)
#pragma unroll
        for (int fn = 0; fn < 4; ++fn)
#pragma unroll
          for (int r = 0; r < 4; ++r)
            Tpc[mh * 32 + fm * 16 + g * 4 + r][nq * 64 + fn * 16 + li] = f2bf(acc[fm][fn][r]);
    }

    asm volatile("s_waitcnt lgkmcnt(0)" ::: "memory");
    __builtin_amdgcn_s_barrier();

    // cc MFMA — wave w: rows [w*16, w*16+16), all 64 cols, K from swizzled LDS
    f4_t s4[4];
#pragma unroll
    for (int fn = 0; fn < 4; ++fn) s4[fn] = f4_t{0.f, 0.f, 0.f, 0.f};
#pragma unroll
    for (int ks = 0; ks < 2; ++ks) {
      bf8_t b[4];
#pragma unroll
      for (int fn = 0; fn < 4; ++fn)
        b[fn] = *chunk(Kt[cur], fn * 16 + li, ks * 4 + g);
#pragma unroll
      for (int fn = 0; fn < 4; ++fn)
        s4[fn] = __builtin_amdgcn_mfma_f32_16x16x32_bf16(q3[ks], b[fn], s4[fn], 0, 0, 0);
    }

    // gather cp/pc from LDS; scale
    float sc[4][4];
#pragma unroll
    for (int fn = 0; fn < 4; ++fn)
#pragma unroll
      for (int r = 0; r < 4; ++r) {
        const int i_loc = w * 16 + g * 4 + r;
        const int j_loc = fn * 16 + li;
        const int d = (j0 + j_loc) - (i0 + i_loc);
        int rc = d;   if (rc > 512) rc = 512;   if (rc < -512) rc = -512;   rc += 512;
        int rc2 = -d; if (rc2 > 512) rc2 = 512; if (rc2 < -512) rc2 = -512; rc2 += 512;
        float v = s4[fn][r] + bf2f(TcpL[i_loc][rc - rbase])
                            + bf2f(Tpc[j_loc][rc2 - rbase2]);
        sc[fn][r] = v * SCALE_;
      }

    // online softmax (rows replicated over 16 lanes li)
    float fac[4];
#pragma unroll
    for (int r = 0; r < 4; ++r) {
      float mx = fmaxf(fmaxf(sc[0][r], sc[1][r]), fmaxf(sc[2][r], sc[3][r]));
#pragma unroll
      for (int off = 1; off < 16; off <<= 1) mx = fmaxf(mx, __shfl_xor(mx, off));
      float mnew = fmaxf(m_r[r], mx);
      fac[r] = __expf(m_r[r] - mnew);
      float rs = 0.f;
#pragma unroll
      for (int fn = 0; fn < 4; ++fn) { sc[fn][r] = __expf(sc[fn][r] - mnew); rs += sc[fn][r]; }
#pragma unroll
      for (int off = 1; off < 16; off <<= 1) rs += __shfl_xor(rs, off);
      l_r[r] = l_r[r] * fac[r] + rs;
      m_r[r] = mnew;
    }
#pragma unroll
    for (int fn = 0; fn < 4; ++fn)
#pragma unroll
      for (int r = 0; r < 4; ++r) acc_o[fn][r] *= fac[r];

    // write P (bf16) to swizzled per-wave LDS
#pragma unroll
    for (int fn = 0; fn < 4; ++fn)
#pragma unroll
      for (int r = 0; r < 4; ++r) {
        const int row = w * 16 + g * 4 + r;
        int byte = row * 128 + (fn * 16 + li) * 2;
        byte ^= (row & 7) << 4;
        *(unsigned short*)((char*)Pl + byte) = f2bf(sc[fn][r]);
      }

    // PV: acc_o += P(16x64) @ V^T  (A from Pl, B from swizzled V_lds)
#pragma unroll
    for (int ks = 0; ks < 2; ++ks) {
      const int arow = w * 16 + li;
      int abyte = arow * 128 + ks * 64 + g * 16;
      abyte ^= (arow & 7) << 4;
      bf8_t a = *(const bf8_t*)((const char*)Pl + abyte);
      bf8_t b[4];
#pragma unroll
      for (int fn2 = 0; fn2 < 4; ++fn2)
        b[fn2] = *chunk(Vl[cur], fn2 * 16 + li, ks * 4 + g);
#pragma unroll
      for (int fn2 = 0; fn2 < 4; ++fn2)
        acc_o[fn2] = __builtin_amdgcn_mfma_f32_16x16x32_bf16(a, b[fn2], acc_o[fn2], 0, 0, 0);
    }
  }

  // epilogue: normalize, write ctx [B*S, E] bf16
#pragma unroll
  for (int fn2 = 0; fn2 < 4; ++fn2)
#pragma unroll
    for (int r = 0; r < 4; ++r) {
      const int row = i0 + w * 16 + g * 4 + r;
      const int d = fn2 * 16 + li;
      float v = acc_o[fn2][r] / l_r[r];
      ctx[((long)bb * 1024 + row) * 768 + h * 64 + d] = f2bf(v);
    }
}

// ---------------- host launch ---------------------------------------------
extern "C" void kernel_launch(void* const* d_in, const int* in_sizes, int n_in,
                              void* d_out, int out_size, void* d_ws, size_t ws_size,
                              hipStream_t stream)
{
  const float* x   = (const float*)d_in[0];
  const float* Wq  = (const float*)d_in[1];
  const float* bq  = (const float*)d_in[2];
  const float* Wk  = (const float*)d_in[3];
  const float* bk  = (const float*)d_in[4];
  const float* Wv  = (const float*)d_in[5];
  const float* bv  = (const float*)d_in[6];
  const float* Wpq = (const float*)d_in[7];
  const float* bpq = (const float*)d_in[8];
  const float* Wpk = (const float*)d_in[9];
  const float* bpk = (const float*)d_in[10];
  const float* rel = (const float*)d_in[11];
  const float* Wo  = (const float*)d_in[12];
  const float* bo  = (const float*)d_in[13];

  char* ws = (char*)d_ws;
  auto alloc = [&](size_t bytes) { char* p = ws; ws += (bytes + 255) & ~(size_t)255; return p; };
  unsigned short* xb   = (unsigned short*)alloc((size_t)4096 * 768 * 2);
  unsigned short* Wqb  = (unsigned short*)alloc((size_t)768 * 768 * 2);
  unsigned short* Wkb  = (unsigned short*)alloc((size_t)768 * 768 * 2);
  unsigned short* Wvb  = (unsigned short*)alloc((size_t)768 * 768 * 2);
  unsigned short* Wpqb = (unsigned short*)alloc((size_t)768 * 768 * 2);
  unsigned short* Wpkb = (unsigned short*)alloc((size_t)768 * 768 * 2);
  unsigned short* Wob  = (unsigned short*)alloc((size_t)768 * 768 * 2);
  unsigned short* relb = (unsigned short*)alloc((size_t)1025 * 768 * 2);
  unsigned short* Qb   = (unsigned short*)alloc((size_t)48 * 1024 * 64 * 2);  // [B,H,S,D]
  unsigned short* Kb   = (unsigned short*)alloc((size_t)48 * 1024 * 64 * 2);  // [B,H,S,D]
  unsigned short* Vt   = (unsigned short*)alloc((size_t)48 * 64 * 1024 * 2);  // [B,H,D,S]
  unsigned short* qrb  = (unsigned short*)alloc((size_t)12 * 1025 * 64 * 2);  // [H,R,D]
  unsigned short* krb  = (unsigned short*)alloc((size_t)12 * 1025 * 64 * 2);
  unsigned short* ctx  = (unsigned short*)alloc((size_t)4096 * 768 * 2);      // [B*S, E]

  CvtArgs ca;
  const float* srcs[8] = {x, Wq, Wk, Wv, Wpq, Wpk, Wo, rel};
  unsigned short* dsts[8] = {xb, Wqb, Wkb, Wvb, Wpqb, Wpkb, Wob, relb};
  const int nch[8] = {786432, 147456, 147456, 147456, 147456, 147456, 147456, 196800};
  int total = 0;
  for (int i = 0; i < 8; ++i) { ca.src[i] = srcs[i]; ca.dst[i] = dsts[i]; ca.nchunks[i] = nch[i]; total += nch[i]; }
  cvt_kernel<<<dim3(2048), dim3(256), 0, stream>>>(ca, total);

  dim3 blk(256);
  // content projections: [4096,768] x [768,768]^T
  gemm_bt<64, 128, MQKV><<<dim3(6, 64, 1), blk, 0, stream>>>(xb, 768, 0, Wqb, 768, 0, Qb, bq, 4096, 768, 768);
  gemm_bt<64, 128, MQKV><<<dim3(6, 64, 1), blk, 0, stream>>>(xb, 768, 0, Wkb, 768, 0, Kb, bk, 4096, 768, 768);
  gemm_bt<64, 128, MVT ><<<dim3(6, 64, 1), blk, 0, stream>>>(xb, 768, 0, Wvb, 768, 0, Vt, bv, 4096, 768, 768);
  // positional projections: [1025,768] x [768,768]^T
  gemm_bt<64, 128, MREL><<<dim3(6, 17, 1), blk, 0, stream>>>(relb, 768, 0, Wpqb, 768, 0, qrb, bpq, 1025, 768, 768);
  gemm_bt<64, 128, MREL><<<dim3(6, 17, 1), blk, 0, stream>>>(relb, 768, 0, Wpkb, 768, 0, krb, bpk, 1025, 768, 768);
  // fused scores(cc+cp+pc) + softmax + PV
  flash_kernel<<<dim3(16, 48), blk, 0, stream>>>(Qb, Kb, krb, qrb, Vt, ctx);
  // output projection: [4096,768] x [768,768]^T -> fp32 d_out
  gemm_bt<64, 128, MOUT><<<dim3(6, 64, 1), blk, 0, stream>>>(ctx, 768, 0, Wob, 768, 0, d_out, bo, 4096, 768, 768);

  (void)in_sizes; (void)n_in; (void)out_size; (void)ws_size;
}